// Round 8
// baseline (116.563 us; speedup 1.0000x reference)
//
#include <hip/hip_runtime.h>

#define MARGIN 0.3f

typedef __attribute__((ext_vector_type(8))) short short8;
typedef __attribute__((ext_vector_type(16))) float floatx16;

// ---- helpers ----------------------------------------------------------------

// fp32 -> bf16 bits, round-to-nearest-even
__device__ __forceinline__ short f2bf(float f) {
    unsigned u = __float_as_uint(f);
    u = u + 0x7fffu + ((u >> 16) & 1u);
    return (short)(u >> 16);
}

// ---- FUSED kernel: stage + 32x32x16 MFMA GEMM + row-min + loss --------------
// R8 = R5's single-kernel fusion + R7's (numerically verified) 32x32x16 core,
// unconfounded: cb-sequential accumulators keep live acc at 32 regs and
// __launch_bounds__(512,1) gives the allocator 256 regs -> no spill (R7's
// WRITE_SIZE=25MB was scratch). Row-min is ATOMIC-FREE: each block plain-
// stores its per-row mins to a private rowmin2d[cgi] slice (same-XCD via the
// bijective swizzle); the rg-finisher min-reduces the 16 slices. No prep
// kernel, no init kernel (one 128B memset), no barriers/waitcnt in the GEMM
// loop (panel staged by own block, one __syncthreads).
// Rationale: counters across R0-R7 indicate issue-throughput-bound execution
// at idle DVFS clocks -> minimize issued instructions and dispatch count.
__global__ __launch_bounds__(512, 1)
void fused_kernel(const float* __restrict__ z1, const float* __restrict__ z2,
                  float* __restrict__ rowmin2d, float* __restrict__ posd,
                  float* __restrict__ psum, unsigned* __restrict__ cnt,
                  float* __restrict__ out, int n)
{
    __shared__ __align__(16) short bt[65536];   // B panel: 512 cols x 128 k bf16 (-2x)
    __shared__ __align__(16) float s2l[512];    // |z2_j|^2, exact fp32
    __shared__ __align__(16) float sq1l[512];   // |z1_i|^2, exact fp32
    __shared__ float lsum[8];
    __shared__ int   fin_s;

    // bijective XCD swizzle (256 blocks = 8 xcd x 32, exact):
    // xcd owns row-groups {2*xcd, 2*xcd+1} x all 16 col-groups.
    const int bid = blockIdx.x;
    const int xcd = bid & 7, idx = bid >> 3;      // idx 0..31
    const int rg  = (xcd << 1) | (idx >> 4);      // row-group 0..15
    const int cgi = idx & 15;                     // col-group 0..15

    const int tid = threadIdx.x, w = tid >> 6, lane = tid & 63;
    const int l31 = lane & 31, hi = lane >> 5;    // 32x32 operand coords
    const int rowbase = rg * 512 + w * 64;        // this wave's 64 rows
    const int colorig = cgi * 512;

    // ---- B stage: thread t owns col colorig+t (128 els, contiguous reads).
    // Fragment-native LDS layout (verified R5-write / R7-read):
    // col c, k -> (c/16)*2048 + (k/32)*512 + ((k%32)/8)*128 + (c%16)*8
    {
        const float4* zb = (const float4*)(z2 + (size_t)(colorig + tid) * 128);
        float s2 = 0.f;
        #pragma unroll
        for (int kk = 0; kk < 4; ++kk) {
            float4 f[8];
            #pragma unroll
            for (int j = 0; j < 8; ++j) f[j] = zb[kk * 8 + j];
            #pragma unroll
            for (int j = 0; j < 8; ++j)
                s2 += f[j].x*f[j].x + f[j].y*f[j].y + f[j].z*f[j].z + f[j].w*f[j].w;
            #pragma unroll
            for (int q = 0; q < 4; ++q) {
                float4 a = f[q * 2], b = f[q * 2 + 1];
                // pre-scale by -2 (exact in bf16: sign/exponent only)
                short8 sc = { f2bf(-2.f*a.x), f2bf(-2.f*a.y), f2bf(-2.f*a.z), f2bf(-2.f*a.w),
                              f2bf(-2.f*b.x), f2bf(-2.f*b.y), f2bf(-2.f*b.z), f2bf(-2.f*b.w) };
                *(short8*)&bt[(tid >> 4) * 2048 + kk * 512 + q * 128 + (tid & 15) * 8] = sc;
            }
        }
        s2l[tid] = s2;
    }

    // ---- A stage: 32x32x16 fragments straight from fp32 + exact sq1 --------
    // af[rb][kk16]: lane holds z1[rowbase + rb*32 + l31][kk16*16 + hi*8 ..+7]
    short8 af[2][8];
    #pragma unroll
    for (int rb = 0; rb < 2; ++rb) {
        const float4* zr = (const float4*)(z1 + (size_t)(rowbase + rb * 32 + l31) * 128);
        float s1p = 0.f;
        #pragma unroll
        for (int kk16 = 0; kk16 < 8; ++kk16) {
            float4 u0 = zr[kk16 * 4 + hi * 2];
            float4 u1 = zr[kk16 * 4 + hi * 2 + 1];
            s1p += u0.x*u0.x + u0.y*u0.y + u0.z*u0.z + u0.w*u0.w
                 + u1.x*u1.x + u1.y*u1.y + u1.z*u1.z + u1.w*u1.w;
            af[rb][kk16] = { f2bf(u0.x), f2bf(u0.y), f2bf(u0.z), f2bf(u0.w),
                             f2bf(u1.x), f2bf(u1.y), f2bf(u1.z), f2bf(u1.w) };
        }
        float s1 = s1p + __shfl_xor(s1p, 32);     // join the two k-halves
        if (hi == 0) sq1l[w * 64 + rb * 32 + l31] = s1;
    }

    // ---- posd stage: this block computes rows rg*512+cgi*32 .. +32 ---------
    {
        int ri = rg * 512 + cgi * 32 + (tid >> 4);
        int e  = (tid & 15) * 8;
        const float4* p1 = (const float4*)(z1 + (size_t)ri * 128 + e);
        const float4* p2 = (const float4*)(z2 + (size_t)ri * 128 + e);
        float4 a0 = p1[0], a1 = p1[1], b0 = p2[0], b1 = p2[1];
        float dx0 = a0.x-b0.x, dy0 = a0.y-b0.y, dz0 = a0.z-b0.z, dw0 = a0.w-b0.w;
        float dx1 = a1.x-b1.x, dy1 = a1.y-b1.y, dz1 = a1.z-b1.z, dw1 = a1.w-b1.w;
        float p2a = dx0*dx0 + dy0*dy0 + dz0*dz0 + dw0*dw0
                  + dx1*dx1 + dy1*dy1 + dz1*dz1 + dw1*dw1;
        #pragma unroll
        for (int m = 8; m >= 1; m >>= 1) p2a += __shfl_xor(p2a, m);
        if ((tid & 15) == 0) posd[ri] = sqrtf(p2a);
    }

    __syncthreads();    // panel + sq arrays resident; loop is free-running

    // per-lane byte offset (shorts) inside a 64-col fragment-native group
    const int lofs = ((lane >> 4) & 1) * 2048 + hi * 128 + (lane & 15) * 8;

    float vmin[2][16];
    #pragma unroll
    for (int rb = 0; rb < 2; ++rb)
        #pragma unroll
        for (int r = 0; r < 16; ++r)
            vmin[rb][r] = 3.0e38f;

    #pragma unroll
    for (int S = 0; S < 8; ++S) {
        const short* bs_ = &bt[S * 8192] + lofs;
        #pragma unroll
        for (int cb = 0; cb < 2; ++cb) {          // cb-sequential: 32 live acc regs
            const float s2v = s2l[S * 64 + cb * 32 + l31];
            const short* base = bs_ + cb * 4096;

            floatx16 a0, a1;                       // acc init = sq2[col]
            #pragma unroll
            for (int r = 0; r < 16; ++r) { a0[r] = s2v; a1[r] = s2v; }

            #pragma unroll
            for (int kk16 = 0; kk16 < 8; ++kk16) {
                short8 b = *(const short8*)(base + (kk16 >> 1) * 512 + (kk16 & 1) * 256);
                a0 = __builtin_amdgcn_mfma_f32_32x32x16_bf16(af[0][kk16], b, a0, 0, 0, 0);
                a1 = __builtin_amdgcn_mfma_f32_32x32x16_bf16(af[1][kk16], b, a1, 0, 0, 0);
            }

            const int cbcol = colorig + S * 64 + cb * 32;
            if (cbcol < rowbase + 64 && rowbase < cbcol + 32) {
                // diagonal overlaps: mask gi == cbcol + l31 (C/D: col=l31,
                // row=(r&3)+8*(r>>2)+4*hi — verified R7, absmax 0)
                #pragma unroll
                for (int r = 0; r < 16; ++r) {
                    int gr = (r & 3) + 8 * (r >> 2) + 4 * hi;
                    int gi0 = rowbase + gr, gi1 = rowbase + 32 + gr;
                    float v0 = (gi0 == cbcol + l31) ? 3.0e38f : a0[r];
                    float v1 = (gi1 == cbcol + l31) ? 3.0e38f : a1[r];
                    vmin[0][r] = fminf(vmin[0][r], v0);
                    vmin[1][r] = fminf(vmin[1][r], v1);
                }
            } else {
                #pragma unroll
                for (int r = 0; r < 16; ++r) {
                    vmin[0][r] = fminf(vmin[0][r], a0[r]);
                    vmin[1][r] = fminf(vmin[1][r], a1[r]);
                }
            }
        }
    }

    // reduce each row's 32 cols (lanes hi*32..+31), plain store to the
    // block's private rowmin2d slice — no atomics, no init required.
    #pragma unroll
    for (int rb = 0; rb < 2; ++rb)
        #pragma unroll
        for (int r = 0; r < 16; ++r) {
            float vm = vmin[rb][r];
            #pragma unroll
            for (int m = 16; m >= 1; m >>= 1)
                vm = fminf(vm, __shfl_xor(vm, m));
            if (l31 == 0)
                rowmin2d[(size_t)cgi * n + rowbase + rb * 32
                         + (r & 3) + 8 * (r >> 2) + 4 * hi] = vm;
        }

    __syncthreads();
    if (tid == 0) {
        __threadfence();    // release: rowmin2d slice + posd visible
        fin_s = (atomicAdd(&cnt[rg], 1u) == 15u);   // 16 col-blocks per rg
    }
    __syncthreads();
    if (!fin_s) return;
    __threadfence();        // acquire: see all 16 slices + posd

    // finisher: loss for rows [rg*512, rg*512+512), thread = one row.
    // min over the 16 col-slices (coalesced per slice), sq1 from LDS.
    {
        int i = rg * 512 + tid;
        float mn = rowmin2d[i];                   // cgi = 0
        #pragma unroll
        for (int c = 1; c < 16; ++c)
            mn = fminf(mn, rowmin2d[(size_t)c * n + i]);
        float hard = sqrtf(fmaxf(sq1l[tid] + mn, 0.0f));
        float l = fmaxf(posd[i] - hard + MARGIN, 0.0f);
        #pragma unroll
        for (int m = 32; m >= 1; m >>= 1) l += __shfl_xor(l, m);
        if (lane == 0) lsum[w] = l;
    }
    __syncthreads();
    if (tid == 0) {
        float t = 0.f;
        #pragma unroll
        for (int i = 0; i < 8; ++i) t += lsum[i];
        atomicExch(&psum[rg], t);                 // device-scope publish
        __threadfence();
        if (atomicAdd(&cnt[16], 1u) == 15u) {     // globally last finisher
            __threadfence();
            float tot = 0.f;
            #pragma unroll
            for (int j = 0; j < 16; ++j)
                tot += atomicAdd(&psum[j], 0.0f); // coherent forced reads
            out[0] = tot / (float)n;              // direct store: no out-init
        }
    }
}

// ---- launch -----------------------------------------------------------------
extern "C" void kernel_launch(void* const* d_in, const int* in_sizes, int n_in,
                              void* d_out, int out_size, void* d_ws, size_t ws_size,
                              hipStream_t stream) {
    const float* z1 = (const float*)d_in[0];
    const float* z2 = (const float*)d_in[1];
    const int n = in_sizes[0] / 128;            // 8192

    char* ws = (char*)d_ws;
    float*    rowmin2d = (float*)ws;                              // 16*n*4 = 512 KB
    float*    posd     = (float*)(ws + (size_t)16 * n * 4);       // 32 KB
    float*    psum     = (float*)(ws + (size_t)17 * n * 4);       // 64 B
    unsigned* cnt      = (unsigned*)(ws + (size_t)17 * n * 4 + 256); // 68 B used
    float*    out      = (float*)d_out;

    hipMemsetAsync(cnt, 0, 128, stream);        // the ONLY init: cnt[0..16]
    fused_kernel<<<(n / 512) * (n / 512), 512, 0, stream>>>(
        z1, z2, rowmin2d, posd, psum, cnt, out, n);
}

// Round 9
// 102.127 us; speedup vs baseline: 1.1414x; 1.1414x over previous
//
#include <hip/hip_runtime.h>

#define MARGIN 0.3f

typedef __attribute__((ext_vector_type(8))) short short8;
typedef __attribute__((ext_vector_type(4))) float floatx4;
typedef __attribute__((ext_vector_type(4))) unsigned uintx4;

// ---- helpers ----------------------------------------------------------------

// packed fp32x2 -> bf16x2 (RNE), one instruction; no builtin on gfx950 (m240)
__device__ __forceinline__ unsigned cvt_pk(float a, float b) {
    unsigned r;
    asm("v_cvt_pk_bf16_f32 %0, %1, %2" : "=v"(r) : "v"(a), "v"(b));
    return r;
}
// same, with FREE negation via VOP3 input modifiers
__device__ __forceinline__ unsigned cvt_pk_neg(float a, float b) {
    unsigned r;
    asm("v_cvt_pk_bf16_f32 %0, -%1, -%2" : "=v"(r) : "v"(a), "v"(b));
    return r;
}
__device__ __forceinline__ short8 make8(unsigned p0, unsigned p1,
                                        unsigned p2, unsigned p3) {
    uintx4 u = { p0, p1, p2, p3 };
    return __builtin_bit_cast(short8, u);
}

// ---- FUSED kernel: stage + 16x16x32 MFMA GEMM + row-min + loss --------------
// R9 = R5's proven-clean fused structure (104 VGPR, no spill, 41 us),
// instruction-thinned under the issue-throughput model (R0-R8 evidence:
// kernels run at idle DVFS clocks; dur tracks issued instructions, every
// latency/occupancy/schedule lever was null):
//  - all fp32->bf16 via v_cvt_pk_bf16_f32 (1 instr / 2 elems, was ~2.5/elem)
//  - scale algebra hoisted: min_j(sq2-2dot) = 2*min_j(0.5*sq2 - dot);
//    B stored negated (free -src modifier), s2l halved once, finisher *2.
//  - R8's atomic-free epilogue: plain-store per-cgi rowmin2d slice
//    (same-XCD via swizzle), in-kernel finisher; no init kernel, no
//    enc/dec, no atomicMin. cnt zeroed by a 128 B memset.
// 32x32 MFMA core is abandoned: it spills at any launch_bounds (R7/R8,
// WRITE_SIZE 25-29 MB scratch signature).
__global__ __launch_bounds__(512, 2)
void fused_kernel(const float* __restrict__ z1, const float* __restrict__ z2,
                  float* __restrict__ rowmin2d, float* __restrict__ posd,
                  float* __restrict__ psum, unsigned* __restrict__ cnt,
                  float* __restrict__ out, int n)
{
    __shared__ __align__(16) short bt[65536];   // B panel: 512 cols x 128 k, NEGATED bf16
    __shared__ __align__(16) float s2l[512];    // 0.5 * |z2_j|^2, exact fp32
    __shared__ __align__(16) float sq1l[512];   // |z1_i|^2, exact fp32
    __shared__ float lsum[8];
    __shared__ int   fin_s;

    // bijective XCD swizzle (256 blocks = 8 xcd x 32, exact):
    // xcd owns row-groups {2*xcd, 2*xcd+1} x all 16 col-groups.
    const int bid = blockIdx.x;
    const int xcd = bid & 7, idx = bid >> 3;      // idx 0..31
    const int rg  = (xcd << 1) | (idx >> 4);      // row-group 0..15
    const int cgi = idx & 15;                     // col-group 0..15

    const int tid = threadIdx.x, w = tid >> 6, lane = tid & 63;
    const int quad = lane >> 4, l15 = lane & 15;
    const int rowbase = rg * 512 + w * 64;        // this wave's 64 rows
    const int colorig = cgi * 512;

    // ---- B stage: thread t owns col colorig+t (128 els, contiguous reads).
    // Fragment-native LDS layout: col c, k ->
    //   (c/16)*2048 + (k/32)*512 + ((k%32)/8)*128 + (c%16)*8
    {
        const float4* zb = (const float4*)(z2 + (size_t)(colorig + tid) * 128);
        float s2 = 0.f;
        #pragma unroll
        for (int kk = 0; kk < 4; ++kk) {
            float4 f[8];
            #pragma unroll
            for (int j = 0; j < 8; ++j) f[j] = zb[kk * 8 + j];
            #pragma unroll
            for (int j = 0; j < 8; ++j)
                s2 += f[j].x*f[j].x + f[j].y*f[j].y + f[j].z*f[j].z + f[j].w*f[j].w;
            #pragma unroll
            for (int q = 0; q < 4; ++q) {
                float4 a = f[q * 2], b = f[q * 2 + 1];
                uintx4 sc = { cvt_pk_neg(a.x, a.y), cvt_pk_neg(a.z, a.w),
                              cvt_pk_neg(b.x, b.y), cvt_pk_neg(b.z, b.w) };
                *(uintx4*)&bt[(tid >> 4) * 2048 + kk * 512 + q * 128 + (tid & 15) * 8] = sc;
            }
        }
        s2l[tid] = 0.5f * s2;                      // halved once (algebra hoist)
    }

    // ---- A stage: bf16 fragments straight from fp32 + exact sq1 ------------
    // af[sm][kk]: lane(quad,l15) <- z1[rowbase+sm*16+l15][kk*32+quad*8 ..+7]
    short8 af[4][4];
    {
        float s1p[4] = {0.f, 0.f, 0.f, 0.f};
        #pragma unroll
        for (int sm = 0; sm < 4; ++sm) {
            const float4* zr = (const float4*)(z1 + (size_t)(rowbase + sm * 16 + l15) * 128);
            #pragma unroll
            for (int kk = 0; kk < 4; ++kk) {
                float4 u0 = zr[kk * 8 + quad * 2];
                float4 u1 = zr[kk * 8 + quad * 2 + 1];
                s1p[sm] += u0.x*u0.x + u0.y*u0.y + u0.z*u0.z + u0.w*u0.w
                         + u1.x*u1.x + u1.y*u1.y + u1.z*u1.z + u1.w*u1.w;
                af[sm][kk] = make8(cvt_pk(u0.x, u0.y), cvt_pk(u0.z, u0.w),
                                   cvt_pk(u1.x, u1.y), cvt_pk(u1.z, u1.w));
            }
        }
        #pragma unroll
        for (int sm = 0; sm < 4; ++sm) {
            float s1 = s1p[sm];
            s1 += __shfl_xor(s1, 16);              // reduce across the 4 quads
            s1 += __shfl_xor(s1, 32);
            if (quad == 0) sq1l[w * 64 + sm * 16 + l15] = s1;
        }
    }

    // ---- posd stage: this block computes rows rg*512+cgi*32 .. +32 ---------
    {
        int ri = rg * 512 + cgi * 32 + (tid >> 4);
        int e  = (tid & 15) * 8;
        const float4* p1 = (const float4*)(z1 + (size_t)ri * 128 + e);
        const float4* p2 = (const float4*)(z2 + (size_t)ri * 128 + e);
        float4 a0 = p1[0], a1 = p1[1], b0 = p2[0], b1 = p2[1];
        float dx0 = a0.x-b0.x, dy0 = a0.y-b0.y, dz0 = a0.z-b0.z, dw0 = a0.w-b0.w;
        float dx1 = a1.x-b1.x, dy1 = a1.y-b1.y, dz1 = a1.z-b1.z, dw1 = a1.w-b1.w;
        float p2a = dx0*dx0 + dy0*dy0 + dz0*dz0 + dw0*dw0
                  + dx1*dx1 + dy1*dy1 + dz1*dz1 + dw1*dw1;
        #pragma unroll
        for (int m = 8; m >= 1; m >>= 1) p2a += __shfl_xor(p2a, m);
        if ((tid & 15) == 0) posd[ri] = sqrtf(p2a);
    }

    __syncthreads();    // panel + sq arrays resident; loop is free-running

    float vmin[4][4];
    #pragma unroll
    for (int sm = 0; sm < 4; ++sm)
        #pragma unroll
        for (int reg = 0; reg < 4; ++reg)
            vmin[sm][reg] = 3.0e38f;

    #pragma unroll
    for (int S = 0; S < 8; ++S) {
        const short* bs_ = &bt[S * 8192];
        #pragma unroll
        for (int hf = 0; hf < 2; ++hf) {
            const int tcol = S * 64 + hf * 32;
            const int colbase = colorig + tcol;
            const float s2v0 = s2l[tcol + l15];          // 0.5*sq2
            const float s2v1 = s2l[tcol + 16 + l15];

            short8 bq[2][4];
            #pragma unroll
            for (int sn = 0; sn < 2; ++sn)
                #pragma unroll
                for (int kk = 0; kk < 4; ++kk)
                    bq[sn][kk] = *(const short8*)(bs_ + hf * 4096 + sn * 2048
                                                  + kk * 512 + lane * 8);

            floatx4 acc[4][2];                           // init = 0.5*sq2[col]
            #pragma unroll
            for (int sm = 0; sm < 4; ++sm)
                #pragma unroll
                for (int reg = 0; reg < 4; ++reg) {
                    acc[sm][0][reg] = s2v0;
                    acc[sm][1][reg] = s2v1;
                }

            __builtin_amdgcn_s_setprio(1);
            #pragma unroll
            for (int kk = 0; kk < 4; ++kk)
                #pragma unroll
                for (int sm = 0; sm < 4; ++sm)
                    #pragma unroll
                    for (int sn = 0; sn < 2; ++sn)       // B negated: acc -= dot
                        acc[sm][sn] = __builtin_amdgcn_mfma_f32_16x16x32_bf16(
                            af[sm][kk], bq[sn][kk], acc[sm][sn], 0, 0, 0);
            __builtin_amdgcn_s_setprio(0);

            // fold: vmin = min(vmin, 0.5*sq2 - dot); mask diagonal if overlap
            if (colbase < rowbase + 64 && rowbase < colbase + 32) {
                #pragma unroll
                for (int sm = 0; sm < 4; ++sm)
                    #pragma unroll
                    for (int reg = 0; reg < 4; ++reg) {
                        int gi = rowbase + sm * 16 + quad * 4 + reg;
                        float v0 = acc[sm][0][reg];
                        float v1 = acc[sm][1][reg];
                        v0 = (gi == colbase + l15)      ? 3.0e38f : v0;
                        v1 = (gi == colbase + 16 + l15) ? 3.0e38f : v1;
                        vmin[sm][reg] = fminf(vmin[sm][reg], fminf(v0, v1));
                    }
            } else {
                #pragma unroll
                for (int sm = 0; sm < 4; ++sm)
                    #pragma unroll
                    for (int reg = 0; reg < 4; ++reg)
                        vmin[sm][reg] = fminf(vmin[sm][reg],
                            fminf(acc[sm][0][reg], acc[sm][1][reg]));
            }
        }
    }

    // reduce each row's cols across the quad's 16 lanes; plain store to the
    // block's private rowmin2d slice — no atomics, no init required.
    // C/D: row = rowbase + sm*16 + quad*4 + reg, cols live in lanes l15.
    #pragma unroll
    for (int sm = 0; sm < 4; ++sm)
        #pragma unroll
        for (int reg = 0; reg < 4; ++reg) {
            float vm = vmin[sm][reg];
            #pragma unroll
            for (int m = 8; m >= 1; m >>= 1)
                vm = fminf(vm, __shfl_xor(vm, m));
            if (l15 == 0)
                rowmin2d[(size_t)cgi * n + rowbase + sm * 16 + quad * 4 + reg] = vm;
        }

    __syncthreads();
    if (tid == 0) {
        __threadfence();    // release: rowmin2d slice + posd visible
        fin_s = (atomicAdd(&cnt[rg], 1u) == 15u);   // 16 col-blocks per rg
    }
    __syncthreads();
    if (!fin_s) return;
    __threadfence();        // acquire: see all 16 slices + posd

    // finisher: loss for rows [rg*512, rg*512+512), thread = one row.
    // min over 16 col-slices (coalesced per slice); sq1 from own LDS.
    {
        int i = rg * 512 + tid;
        float mn = rowmin2d[i];                   // cgi = 0
        #pragma unroll
        for (int c = 1; c < 16; ++c)
            mn = fminf(mn, rowmin2d[(size_t)c * n + i]);
        // hard^2 = sq1 + min_j(sq2 - 2dot) = sq1 + 2*mn
        float hard = sqrtf(fmaxf(fmaf(2.0f, mn, sq1l[tid]), 0.0f));
        float l = fmaxf(posd[i] - hard + MARGIN, 0.0f);
        #pragma unroll
        for (int m = 32; m >= 1; m >>= 1) l += __shfl_xor(l, m);
        if (lane == 0) lsum[w] = l;
    }
    __syncthreads();
    if (tid == 0) {
        float t = 0.f;
        #pragma unroll
        for (int i = 0; i < 8; ++i) t += lsum[i];
        atomicExch(&psum[rg], t);                 // device-scope publish
        __threadfence();
        if (atomicAdd(&cnt[16], 1u) == 15u) {     // globally last finisher
            __threadfence();
            float tot = 0.f;
            #pragma unroll
            for (int j = 0; j < 16; ++j)
                tot += atomicAdd(&psum[j], 0.0f); // coherent forced reads
            out[0] = tot / (float)n;              // direct store: no out-init
        }
    }
}

// ---- launch -----------------------------------------------------------------
extern "C" void kernel_launch(void* const* d_in, const int* in_sizes, int n_in,
                              void* d_out, int out_size, void* d_ws, size_t ws_size,
                              hipStream_t stream) {
    const float* z1 = (const float*)d_in[0];
    const float* z2 = (const float*)d_in[1];
    const int n = in_sizes[0] / 128;            // 8192

    char* ws = (char*)d_ws;
    float*    rowmin2d = (float*)ws;                              // 16*n*4 = 512 KB
    float*    posd     = (float*)(ws + (size_t)16 * n * 4);       // 32 KB
    float*    psum     = (float*)(ws + (size_t)17 * n * 4);       // 64 B
    unsigned* cnt      = (unsigned*)(ws + (size_t)17 * n * 4 + 256); // 128 B used
    float*    out      = (float*)d_out;

    hipMemsetAsync(cnt, 0, 128, stream);        // the ONLY init: cnt[0..31]
    fused_kernel<<<(n / 512) * (n / 512), 512, 0, stream>>>(
        z1, z2, rowmin2d, posd, psum, cnt, out, n);
}

// Round 10
// 93.224 us; speedup vs baseline: 1.2503x; 1.0955x over previous
//
#include <hip/hip_runtime.h>

#define MARGIN 0.3f

typedef __attribute__((ext_vector_type(8))) short short8;
typedef __attribute__((ext_vector_type(4))) float floatx4;

// ---- helpers ----------------------------------------------------------------

// fp32 -> bf16 bits, round-to-nearest-even (compiler-scheduled; NO inline asm
// — R9 proved hand-written v_cvt_pk_bf16_f32 serializes staging, +18% dur)
__device__ __forceinline__ short f2bf(float f) {
    unsigned u = __float_as_uint(f);
    u = u + 0x7fffu + ((u >> 16) & 1u);
    return (short)(u >> 16);
}

// direct global->LDS DMA (no VGPR round-trip). LDS dest is wave-uniform
// base + lane*size — all call sites below respect that.
__device__ __forceinline__ void gload_lds16(const void* g, void* l) {
    __builtin_amdgcn_global_load_lds(
        (const __attribute__((address_space(1))) void*)g,
        (__attribute__((address_space(3))) void*)l, 16, 0, 0);
}
__device__ __forceinline__ void gload_lds4(const void* g, void* l) {
    __builtin_amdgcn_global_load_lds(
        (const __attribute__((address_space(1))) void*)g,
        (__attribute__((address_space(3))) void*)l, 4, 0, 0);
}

// Fragment-native global layout: element (row, k) with g16=row/16, r=row%16,
// kk=k/32, q=(k%32)/8, e=k%8 lives at  g16*2048 + kk*512 + q*128 + r*8 + e.
// A wave's fragment load for (g16, kk) is base + lane*8 shorts = 64 lanes x
// 16 B CONTIGUOUS — the global->LDS stage is a linear memcpy.

// ---- kernel 1: prepass (R4-proven; rowmin/out init deleted) ------------------
__global__ void prep_kernel(const float* __restrict__ z1, const float* __restrict__ z2,
                            short* __restrict__ z1b, short* __restrict__ z2b,
                            float* __restrict__ sq1, float* __restrict__ sq2,
                            float* __restrict__ posd, unsigned* __restrict__ cnt) {
    int h = blockIdx.x * 256 + threadIdx.x;     // 0 .. n*16-1
    int row = h >> 4, p = h & 15;
    int kk = p >> 2, q = p & 3;
    int f0 = row * 32 + kk * 8 + q * 2;         // first float4 index
    float4 fa0 = ((const float4*)z1)[f0], fa1 = ((const float4*)z1)[f0 + 1];
    float4 fb0 = ((const float4*)z2)[f0], fb1 = ((const float4*)z2)[f0 + 1];
    short8 sa = { f2bf(fa0.x), f2bf(fa0.y), f2bf(fa0.z), f2bf(fa0.w),
                  f2bf(fa1.x), f2bf(fa1.y), f2bf(fa1.z), f2bf(fa1.w) };
    // B pre-scaled by -2 (exact in bf16): GEMM accumulates sq2 - 2*dot directly
    short8 sb = { f2bf(-2.f*fb0.x), f2bf(-2.f*fb0.y), f2bf(-2.f*fb0.z), f2bf(-2.f*fb0.w),
                  f2bf(-2.f*fb1.x), f2bf(-2.f*fb1.y), f2bf(-2.f*fb1.z), f2bf(-2.f*fb1.w) };
    size_t off = (size_t)(row >> 4) * 2048 + kk * 512 + q * 128 + (row & 15) * 8;
    __builtin_nontemporal_store(sa, (short8*)&z1b[off]);
    __builtin_nontemporal_store(sb, (short8*)&z2b[off]);

    float s1 = fa0.x*fa0.x + fa0.y*fa0.y + fa0.z*fa0.z + fa0.w*fa0.w
             + fa1.x*fa1.x + fa1.y*fa1.y + fa1.z*fa1.z + fa1.w*fa1.w;
    float s2 = fb0.x*fb0.x + fb0.y*fb0.y + fb0.z*fb0.z + fb0.w*fb0.w
             + fb1.x*fb1.x + fb1.y*fb1.y + fb1.z*fb1.z + fb1.w*fb1.w;
    float dx0 = fa0.x-fb0.x, dy0 = fa0.y-fb0.y, dz0 = fa0.z-fb0.z, dw0 = fa0.w-fb0.w;
    float dx1 = fa1.x-fb1.x, dy1 = fa1.y-fb1.y, dz1 = fa1.z-fb1.z, dw1 = fa1.w-fb1.w;
    float p2 = dx0*dx0 + dy0*dy0 + dz0*dz0 + dw0*dw0
             + dx1*dx1 + dy1*dy1 + dz1*dz1 + dw1*dw1;
    #pragma unroll
    for (int m = 8; m >= 1; m >>= 1) {          // 16 threads per row
        s1 += __shfl_xor(s1, m);
        s2 += __shfl_xor(s2, m);
        p2 += __shfl_xor(p2, m);
    }
    if (p == 0) {
        __builtin_nontemporal_store(s1, &sq1[row]);
        __builtin_nontemporal_store(s2, &sq2[row]);
        __builtin_nontemporal_store(sqrtf(p2), &posd[row]);
    }

    if (blockIdx.x == 0 && threadIdx.x < 32) cnt[threadIdx.x] = 0u;
}

// ---- kernel 2: 512x512-tile full-panel MFMA GEMM + row-min + fused loss -----
// R10 = R4's gemm (best-total family: R3 84.0 / R4 85.0) with the ONLY change
// being the twice-validated atomic-free epilogue (R8/R9, absmax 0.0):
// each block plain-stores its 512 per-row mins into a private rowmin2d[cgi]
// slice (all 16 blocks of an rg share one XCD via the bijective swizzle, so
// slice visibility needs only the existing threadfence/cnt handshake); the
// rg-finisher min-reduces 16 slices with plain coalesced loads; the LAST of
// the 16 finishers sums psum[] and writes out directly. Deleted: all
// atomicMin, enc/dec encoding, forced-atomic rereads, rowmin init, out init.
__global__ __launch_bounds__(512, 2)
void gemm_min_kernel(const short* __restrict__ z1b, const short* __restrict__ z2b,
                     const float* __restrict__ sq1, const float* __restrict__ sq2,
                     const float* __restrict__ posd,
                     float* __restrict__ rowmin2d, unsigned* __restrict__ cnt,
                     float* __restrict__ psum, float* __restrict__ out, int n)
{
    __shared__ __align__(16) short sb[8][8192];   // 8 x (64 cols x 128 k) bf16
    __shared__ __align__(16) float s2l[512];      // sq2 slice for block's cols
    __shared__ float lsum[8];
    __shared__ int   fin_s;

    // bijective XCD swizzle (256 blocks = 8 xcd x 32, exact):
    // xcd owns row-groups {2*xcd, 2*xcd+1} x all 16 col-groups.
    const int bid = blockIdx.x;
    const int xcd = bid & 7, idx = bid >> 3;      // idx 0..31
    const int rg  = (xcd << 1) | (idx >> 4);      // row-group 0..15
    const int cgi = idx & 15;                     // col-group 0..15

    const int tid = threadIdx.x, w = tid >> 6, lane = tid & 63;
    const int quad = lane >> 4, l15 = lane & 15;
    const int rowbase = rg * 512 + w * 64;        // this wave's 64 rows
    const int colorig = cgi * 512;

    const short* gb = z2b + (size_t)(cgi * 32) * 2048;   // block's B panel

    // ---- prologue: issue EVERYTHING. per-wave vmem issue order (uniform):
    //   buf0 (2) | s2l (1) | af (16) | buf1..7 (2 each) = 33 outstanding.
    // sched_barrier(0) pins group order so counted vmcnt stays sound.
    #pragma unroll
    for (int o = 0; o < 2; ++o)
        gload_lds16(gb + (tid + o * 512) * 8, &sb[0][(tid + o * 512) * 8]);
    __builtin_amdgcn_sched_barrier(0);
    gload_lds4(sq2 + colorig + tid, &s2l[tid]);
    __builtin_amdgcn_sched_barrier(0);

    // persistent A fragments: af[sm][kk] = A[m = l15 + sm*16 (+rowbase)][kk*32+quad*8 ..+7]
    short8 af[4][4];
    #pragma unroll
    for (int sm = 0; sm < 4; ++sm) {
        const short* pa = z1b + (size_t)(rg * 32 + w * 4 + sm) * 2048 + lane * 8;
        #pragma unroll
        for (int kk = 0; kk < 4; ++kk)
            af[sm][kk] = *(const short8*)(pa + kk * 512);
    }
    __builtin_amdgcn_sched_barrier(0);
    #pragma unroll
    for (int s = 1; s < 8; ++s) {
        #pragma unroll
        for (int o = 0; o < 2; ++o)
            gload_lds16(gb + (size_t)s * 8192 + (tid + o * 512) * 8,
                        &sb[s][(tid + o * 512) * 8]);
        __builtin_amdgcn_sched_barrier(0);
    }

    float vmin[4][4];
    #pragma unroll
    for (int sm = 0; sm < 4; ++sm)
        #pragma unroll
        for (int reg = 0; reg < 4; ++reg)
            vmin[sm][reg] = 3.0e38f;

    // superphase S: wait own stage loads for buf S (counted — later bufs stay
    // in flight), barrier for cross-wave visibility, then pure LDS+MFMA+fmin.
#define SUPERPHASE(S, VMTXT)                                                   \
    do {                                                                       \
        asm volatile("s_waitcnt vmcnt(" VMTXT ")" ::: "memory");               \
        __builtin_amdgcn_sched_barrier(0);                                     \
        __builtin_amdgcn_s_barrier();                                          \
        __builtin_amdgcn_sched_barrier(0);                                     \
        const short* bs_ = &sb[S][0];                                          \
        _Pragma("unroll")                                                      \
        for (int hf = 0; hf < 2; ++hf) {                                       \
            const int tcol = (S) * 64 + hf * 32;                               \
            const int colbase = colorig + tcol;                                \
            const float s2v0 = s2l[tcol + l15];                                \
            const float s2v1 = s2l[tcol + 16 + l15];                           \
            short8 bq[2][4];                                                   \
            _Pragma("unroll")                                                  \
            for (int sn = 0; sn < 2; ++sn)                                     \
                _Pragma("unroll")                                              \
                for (int kk = 0; kk < 4; ++kk)                                 \
                    bq[sn][kk] = *(const short8*)(bs_ + hf * 4096 + sn * 2048  \
                                                  + kk * 512 + lane * 8);      \
            floatx4 acc[4][2];                                                 \
            _Pragma("unroll")                                                  \
            for (int sm = 0; sm < 4; ++sm) {                                   \
                _Pragma("unroll")                                              \
                for (int reg = 0; reg < 4; ++reg) {                            \
                    acc[sm][0][reg] = s2v0;                                    \
                    acc[sm][1][reg] = s2v1;                                    \
                }                                                              \
            }                                                                  \
            __builtin_amdgcn_s_setprio(1);                                     \
            _Pragma("unroll")                                                  \
            for (int kk = 0; kk < 4; ++kk)                                     \
                _Pragma("unroll")                                              \
                for (int sm = 0; sm < 4; ++sm)                                 \
                    _Pragma("unroll")                                          \
                    for (int sn = 0; sn < 2; ++sn)                             \
                        acc[sm][sn] = __builtin_amdgcn_mfma_f32_16x16x32_bf16( \
                            af[sm][kk], bq[sn][kk], acc[sm][sn], 0, 0, 0);     \
            __builtin_amdgcn_s_setprio(0);                                     \
            if (colbase < rowbase + 64 && rowbase < colbase + 32) {            \
                _Pragma("unroll")                                              \
                for (int sm = 0; sm < 4; ++sm)                                 \
                    _Pragma("unroll")                                          \
                    for (int reg = 0; reg < 4; ++reg) {                        \
                        int gi = rowbase + sm * 16 + quad * 4 + reg;           \
                        float v0 = acc[sm][0][reg];                            \
                        float v1 = acc[sm][1][reg];                            \
                        v0 = (gi == colbase + l15)      ? 3.0e38f : v0;        \
                        v1 = (gi == colbase + 16 + l15) ? 3.0e38f : v1;        \
                        vmin[sm][reg] = fminf(vmin[sm][reg], fminf(v0, v1));   \
                    }                                                          \
            } else {                                                           \
                _Pragma("unroll")                                              \
                for (int sm = 0; sm < 4; ++sm)                                 \
                    _Pragma("unroll")                                          \
                    for (int reg = 0; reg < 4; ++reg)                          \
                        vmin[sm][reg] = fminf(vmin[sm][reg],                   \
                            fminf(acc[sm][0][reg], acc[sm][1][reg]));          \
            }                                                                  \
        }                                                                      \
    } while (0)

    SUPERPHASE(0, "14");
    SUPERPHASE(1, "12");
    SUPERPHASE(2, "10");
    SUPERPHASE(3, "8");
    SUPERPHASE(4, "6");
    SUPERPHASE(5, "4");
    SUPERPHASE(6, "2");
    SUPERPHASE(7, "0");
#undef SUPERPHASE

    // reduce each row's cols across the quad's 16 lanes; PLAIN store to the
    // block's private rowmin2d slice — no atomics, no init required.
    #pragma unroll
    for (int sm = 0; sm < 4; ++sm)
        #pragma unroll
        for (int reg = 0; reg < 4; ++reg) {
            float vm = vmin[sm][reg];
            #pragma unroll
            for (int m = 8; m >= 1; m >>= 1)
                vm = fminf(vm, __shfl_xor(vm, m));
            if (l15 == 0)
                rowmin2d[(size_t)cgi * n + rowbase + sm * 16 + quad * 4 + reg] = vm;
        }

    __syncthreads();
    if (tid == 0) {
        __threadfence();    // release: this block's slice visible before bump
        fin_s = (atomicAdd(&cnt[rg], 1u) == 15u);   // 16 col-blocks per rg
    }
    __syncthreads();
    if (!fin_s) return;
    __threadfence();        // acquire: see all 16 slices (same-XCD by swizzle)

    // finisher: loss for rows [rg*512, rg*512+512), thread = one row.
    // min over 16 col-slices with plain coalesced loads.
    {
        int i = rg * 512 + tid;
        float mn = rowmin2d[i];                   // cgi = 0
        #pragma unroll
        for (int c = 1; c < 16; ++c)
            mn = fminf(mn, rowmin2d[(size_t)c * n + i]);
        // rowmin value = sq2 - 2*dot (acc-init + prescale), so hard^2 = sq1 + mn
        float hard = sqrtf(fmaxf(sq1[i] + mn, 0.0f));
        float l = fmaxf(posd[i] - hard + MARGIN, 0.0f);
        #pragma unroll
        for (int m = 32; m >= 1; m >>= 1) l += __shfl_xor(l, m);
        if (lane == 0) lsum[w] = l;
    }
    __syncthreads();
    if (tid == 0) {
        float t = 0.f;
        #pragma unroll
        for (int i = 0; i < 8; ++i) t += lsum[i];
        atomicExch(&psum[rg], t);                 // device-scope publish
        __threadfence();
        if (atomicAdd(&cnt[16], 1u) == 15u) {     // globally last finisher
            __threadfence();
            float tot = 0.f;
            #pragma unroll
            for (int j = 0; j < 16; ++j)
                tot += atomicAdd(&psum[j], 0.0f); // coherent forced reads
            out[0] = tot / (float)n;              // direct store: no out init
        }
    }
}

// ---- launch -----------------------------------------------------------------
extern "C" void kernel_launch(void* const* d_in, const int* in_sizes, int n_in,
                              void* d_out, int out_size, void* d_ws, size_t ws_size,
                              hipStream_t stream) {
    const float* z1 = (const float*)d_in[0];
    const float* z2 = (const float*)d_in[1];
    const int n = in_sizes[0] / 128;            // 8192

    char* ws = (char*)d_ws;
    short*    z1b      = (short*)ws;                                    // 2 MB
    short*    z2b      = (short*)(ws + (size_t)n * 128 * 2);            // 2 MB
    float*    sq1      = (float*)(ws + (size_t)n * 128 * 4);            // 32 KB
    float*    sq2      = (float*)(ws + (size_t)n * 128 * 4 + n * 4);    // 32 KB
    float*    posd     = (float*)(ws + (size_t)n * 128 * 4 + n * 8);    // 32 KB
    float*    rowmin2d = (float*)(ws + (size_t)n * 128 * 4 + n * 12);   // 512 KB
    unsigned* cnt      = (unsigned*)(ws + (size_t)n * 128 * 4 + n * 12
                                     + (size_t)16 * n * 4);             // 128 B
    float*    psum     = (float*)(ws + (size_t)n * 128 * 4 + n * 12
                                  + (size_t)16 * n * 4 + 128);          // 64 B
    float*    out      = (float*)d_out;

    prep_kernel<<<n / 16, 256, 0, stream>>>(z1, z2, z1b, z2b, sq1, sq2, posd, cnt);
    gemm_min_kernel<<<(n / 512) * (n / 512), 512, 0, stream>>>(
        z1b, z2b, sq1, sq2, posd, rowmin2d, cnt, psum, out, n);
}

// Round 11
// 84.087 us; speedup vs baseline: 1.3862x; 1.1087x over previous
//
#include <hip/hip_runtime.h>

#define MARGIN 0.3f

typedef __attribute__((ext_vector_type(8))) short short8;
typedef __attribute__((ext_vector_type(4))) float floatx4;

// ---- helpers ----------------------------------------------------------------

// order-preserving float->uint encoding so unsigned atomicMin == float min
__device__ __forceinline__ unsigned enc_f32(float f) {
    unsigned u = __float_as_uint(f);
    return (u & 0x80000000u) ? ~u : (u | 0x80000000u);
}
__device__ __forceinline__ float dec_f32(unsigned u) {
    return (u & 0x80000000u) ? __uint_as_float(u & 0x7fffffffu)
                             : __uint_as_float(~u);
}
// fp32 -> bf16 bits, round-to-nearest-even
__device__ __forceinline__ short f2bf(float f) {
    unsigned u = __float_as_uint(f);
    u = u + 0x7fffu + ((u >> 16) & 1u);
    return (short)(u >> 16);
}

// direct global->LDS DMA (no VGPR round-trip). LDS dest is wave-uniform
// base + lane*size — all call sites below are thread-linear.
__device__ __forceinline__ void gload_lds16(const void* g, void* l) {
    __builtin_amdgcn_global_load_lds(
        (const __attribute__((address_space(1))) void*)g,
        (__attribute__((address_space(3))) void*)l, 16, 0, 0);
}
__device__ __forceinline__ void gload_lds4(const void* g, void* l) {
    __builtin_amdgcn_global_load_lds(
        (const __attribute__((address_space(1))) void*)g,
        (__attribute__((address_space(3))) void*)l, 4, 0, 0);
}

// Fragment-native global layout: element (row, k) with g16=row/16, r=row%16,
// kk=k/32, q=(k%32)/8, e=k%8 lives at  g16*2048 + kk*512 + q*128 + r*8 + e.
// A wave's fragment load for (g16, kk) is base + lane*8 shorts = 64 lanes x
// 16 B CONTIGUOUS — the global->LDS stage is a linear memcpy.

// ---- kernel 1: prepass -------------------------------------------------------
__global__ void prep_kernel(const float* __restrict__ z1, const float* __restrict__ z2,
                            short* __restrict__ z1b, short* __restrict__ z2b,
                            float* __restrict__ sq1, float* __restrict__ sq2,
                            float* __restrict__ posd, unsigned* __restrict__ rowmin,
                            unsigned* __restrict__ cnt, float* __restrict__ out) {
    int h = blockIdx.x * 256 + threadIdx.x;     // 0 .. n*16-1
    int row = h >> 4, p = h & 15;
    int kk = p >> 2, q = p & 3;
    int f0 = row * 32 + kk * 8 + q * 2;         // first float4 index
    float4 fa0 = ((const float4*)z1)[f0], fa1 = ((const float4*)z1)[f0 + 1];
    float4 fb0 = ((const float4*)z2)[f0], fb1 = ((const float4*)z2)[f0 + 1];
    short8 sa = { f2bf(fa0.x), f2bf(fa0.y), f2bf(fa0.z), f2bf(fa0.w),
                  f2bf(fa1.x), f2bf(fa1.y), f2bf(fa1.z), f2bf(fa1.w) };
    short8 sb = { f2bf(fb0.x), f2bf(fb0.y), f2bf(fb0.z), f2bf(fb0.w),
                  f2bf(fb1.x), f2bf(fb1.y), f2bf(fb1.z), f2bf(fb1.w) };
    size_t off = (size_t)(row >> 4) * 2048 + kk * 512 + q * 128 + (row & 15) * 8;
    *(short8*)&z1b[off] = sa;
    *(short8*)&z2b[off] = sb;

    float s1 = fa0.x*fa0.x + fa0.y*fa0.y + fa0.z*fa0.z + fa0.w*fa0.w
             + fa1.x*fa1.x + fa1.y*fa1.y + fa1.z*fa1.z + fa1.w*fa1.w;
    float s2 = fb0.x*fb0.x + fb0.y*fb0.y + fb0.z*fb0.z + fb0.w*fb0.w
             + fb1.x*fb1.x + fb1.y*fb1.y + fb1.z*fb1.z + fb1.w*fb1.w;
    float dx0 = fa0.x-fb0.x, dy0 = fa0.y-fb0.y, dz0 = fa0.z-fb0.z, dw0 = fa0.w-fb0.w;
    float dx1 = fa1.x-fb1.x, dy1 = fa1.y-fb1.y, dz1 = fa1.z-fb1.z, dw1 = fa1.w-fb1.w;
    float p2 = dx0*dx0 + dy0*dy0 + dz0*dz0 + dw0*dw0
             + dx1*dx1 + dy1*dy1 + dz1*dz1 + dw1*dw1;
    #pragma unroll
    for (int m = 8; m >= 1; m >>= 1) {          // 16 threads per row
        s1 += __shfl_xor(s1, m);
        s2 += __shfl_xor(s2, m);
        p2 += __shfl_xor(p2, m);
    }
    if (p == 0) { sq1[row] = s1; sq2[row] = s2; posd[row] = sqrtf(p2); }

    if (threadIdx.x < 16) rowmin[blockIdx.x * 16 + threadIdx.x] = 0xFFFFFFFFu;
    if (blockIdx.x == 0) {
        if (threadIdx.x < 32) cnt[threadIdx.x] = 0u;
        if (threadIdx.x == 0) out[0] = 0.0f;
    }
}

// ---- kernel 2: 512x512-tile full-panel MFMA GEMM + row-min + fused loss -----
// grid 256 linear = EXACTLY 1 block/CU (single pass). Block = 512 threads =
// 8 waves; wave w owns 64 rows. XCD-bijective swizzle: xcd = bid%8 owns
// row-groups {2*xcd, 2*xcd+1} x all 16 col-groups -> per-XCD working set
// (2 A-panels 256 KB + B 2 MB) < 4 MB L2.
// B panel (512 cols x 128 k = 128 KB) fully issued in prologue as 8 x 16 KB
// LDS buffers; superphase S waits vmcnt(2*(7-S)) — later buffers stay in
// flight, memory latency paid once. Zero global traffic in the loop.
// [Session-final: best-measured configuration, 84.0 us total (R3).]
__global__ __launch_bounds__(512, 2)
void gemm_min_kernel(const short* __restrict__ z1b, const short* __restrict__ z2b,
                     const float* __restrict__ sq1, const float* __restrict__ sq2,
                     const float* __restrict__ posd,
                     unsigned* __restrict__ rowmin, unsigned* __restrict__ cnt,
                     float* __restrict__ out, int n)
{
    __shared__ __align__(16) short sb[8][8192];   // 8 x (64 cols x 128 k) bf16
    __shared__ __align__(16) float s2l[512];      // sq2 slice for block's cols
    __shared__ float lsum[8];
    __shared__ int   fin_s;

    // bijective XCD swizzle (256 blocks = 8 xcd x 32, exact)
    const int bid = blockIdx.x;
    const int xcd = bid & 7, idx = bid >> 3;      // idx 0..31
    const int rg  = (xcd << 1) | (idx >> 4);      // row-group 0..15
    const int cgi = idx & 15;                     // col-group 0..15

    const int tid = threadIdx.x, w = tid >> 6, lane = tid & 63;
    const int quad = lane >> 4, l15 = lane & 15;
    const int rowbase = rg * 512 + w * 64;        // this wave's 64 rows
    const int colorig = cgi * 512;

    const short* gb = z2b + (size_t)(cgi * 32) * 2048;   // block's B panel

    // ---- prologue: issue EVERYTHING. vmem issue order (per wave, uniform):
    //   buf0 (2) | s2l (1) | af (16) | buf1..7 (2 each) = 33 outstanding.
    // sched_barrier(0) pins group order so counted vmcnt stays sound.
    #pragma unroll
    for (int o = 0; o < 2; ++o)
        gload_lds16(gb + (tid + o * 512) * 8, &sb[0][(tid + o * 512) * 8]);
    __builtin_amdgcn_sched_barrier(0);
    gload_lds4(sq2 + colorig + tid, &s2l[tid]);
    __builtin_amdgcn_sched_barrier(0);

    // persistent A fragments: af[sm][kk] = A[m = l15 + sm*16 (+rowbase)][kk*32+quad*8 ..+7]
    short8 af[4][4];
    #pragma unroll
    for (int sm = 0; sm < 4; ++sm) {
        const short* pa = z1b + (size_t)(rg * 32 + w * 4 + sm) * 2048 + lane * 8;
        #pragma unroll
        for (int kk = 0; kk < 4; ++kk)
            af[sm][kk] = *(const short8*)(pa + kk * 512);
    }
    __builtin_amdgcn_sched_barrier(0);
    #pragma unroll
    for (int s = 1; s < 8; ++s) {
        #pragma unroll
        for (int o = 0; o < 2; ++o)
            gload_lds16(gb + (size_t)s * 8192 + (tid + o * 512) * 8,
                        &sb[s][(tid + o * 512) * 8]);
        __builtin_amdgcn_sched_barrier(0);
    }

    float vmin[4][4];
    #pragma unroll
    for (int sm = 0; sm < 4; ++sm)
        #pragma unroll
        for (int reg = 0; reg < 4; ++reg)
            vmin[sm][reg] = 3.0e38f;

    // superphase S: wait own stage loads for buf S (counted — later bufs stay
    // in flight), barrier for cross-wave visibility, then pure LDS+MFMA+VALU.
#define SUPERPHASE(S, VMTXT)                                                   \
    do {                                                                       \
        asm volatile("s_waitcnt vmcnt(" VMTXT ")" ::: "memory");               \
        __builtin_amdgcn_sched_barrier(0);                                     \
        __builtin_amdgcn_s_barrier();                                          \
        __builtin_amdgcn_sched_barrier(0);                                     \
        const short* bs_ = &sb[S][0];                                          \
        _Pragma("unroll")                                                      \
        for (int hf = 0; hf < 2; ++hf) {                                       \
            const int tcol = (S) * 64 + hf * 32;                               \
            const int colbase = colorig + tcol;                                \
            const float s2v0 = s2l[tcol + l15];                                \
            const float s2v1 = s2l[tcol + 16 + l15];                           \
            short8 bq[2][4];                                                   \
            _Pragma("unroll")                                                  \
            for (int sn = 0; sn < 2; ++sn)                                     \
                _Pragma("unroll")                                              \
                for (int kk = 0; kk < 4; ++kk)                                 \
                    bq[sn][kk] = *(const short8*)(bs_ + hf * 4096 + sn * 2048  \
                                                  + kk * 512 + lane * 8);      \
            floatx4 acc[4][2];                                                 \
            _Pragma("unroll")                                                  \
            for (int sm = 0; sm < 4; ++sm)                                     \
                _Pragma("unroll")                                              \
                for (int sn = 0; sn < 2; ++sn)                                 \
                    acc[sm][sn] = (floatx4)0.0f;                               \
            _Pragma("unroll")                                                  \
            for (int kk = 0; kk < 4; ++kk)                                     \
                _Pragma("unroll")                                              \
                for (int sm = 0; sm < 4; ++sm)                                 \
                    _Pragma("unroll")                                          \
                    for (int sn = 0; sn < 2; ++sn)                             \
                        acc[sm][sn] = __builtin_amdgcn_mfma_f32_16x16x32_bf16( \
                            af[sm][kk], bq[sn][kk], acc[sm][sn], 0, 0, 0);     \
            if (colbase < rowbase + 64 && rowbase < colbase + 32) {            \
                _Pragma("unroll")                                              \
                for (int sm = 0; sm < 4; ++sm)                                 \
                    _Pragma("unroll")                                          \
                    for (int reg = 0; reg < 4; ++reg) {                        \
                        int gi = rowbase + sm * 16 + quad * 4 + reg;           \
                        float v0 = fmaf(-2.0f, acc[sm][0][reg], s2v0);         \
                        float v1 = fmaf(-2.0f, acc[sm][1][reg], s2v1);         \
                        v0 = (gi == colbase + l15)      ? 3.0e38f : v0;        \
                        v1 = (gi == colbase + 16 + l15) ? 3.0e38f : v1;        \
                        vmin[sm][reg] = fminf(vmin[sm][reg], fminf(v0, v1));   \
                    }                                                          \
            } else {                                                           \
                _Pragma("unroll")                                              \
                for (int sm = 0; sm < 4; ++sm)                                 \
                    _Pragma("unroll")                                          \
                    for (int reg = 0; reg < 4; ++reg) {                        \
                        float v0 = fmaf(-2.0f, acc[sm][0][reg], s2v0);         \
                        float v1 = fmaf(-2.0f, acc[sm][1][reg], s2v1);         \
                        vmin[sm][reg] = fminf(vmin[sm][reg], fminf(v0, v1));   \
                    }                                                          \
            }                                                                  \
        }                                                                      \
    } while (0)

    SUPERPHASE(0, "14");
    SUPERPHASE(1, "12");
    SUPERPHASE(2, "10");
    SUPERPHASE(3, "8");
    SUPERPHASE(4, "6");
    SUPERPHASE(5, "4");
    SUPERPHASE(6, "2");
    SUPERPHASE(7, "0");
#undef SUPERPHASE

    // min across each quad's 16 lanes, one atomicMin per row
    #pragma unroll
    for (int sm = 0; sm < 4; ++sm)
        #pragma unroll
        for (int reg = 0; reg < 4; ++reg) {
            float vm = vmin[sm][reg];
            #pragma unroll
            for (int m = 8; m >= 1; m >>= 1)
                vm = fminf(vm, __shfl_xor(vm, m));
            if (l15 == 0)
                atomicMin(&rowmin[rowbase + sm * 16 + quad * 4 + reg], enc_f32(vm));
        }

    __syncthreads();
    if (tid == 0) {
        __threadfence();    // release: this block's mins visible before bump
        fin_s = (atomicAdd(&cnt[rg], 1u) == 15u);   // 16 col-blocks per rg
    }
    __syncthreads();
    if (!fin_s) return;
    __threadfence();        // acquire: see all 16 blocks' mins

    // fused loss for rows [rg*512, rg*512+512): thread = one row
    {
        int i = rg * 512 + tid;
        unsigned rm = atomicMin(&rowmin[i], 0xFFFFFFFFu);   // coherent forced read
        float hard = sqrtf(fmaxf(sq1[i] + dec_f32(rm), 0.0f));
        float l = fmaxf(posd[i] - hard + MARGIN, 0.0f);
        #pragma unroll
        for (int m = 32; m >= 1; m >>= 1) l += __shfl_xor(l, m);
        if (lane == 0) lsum[w] = l;
    }
    __syncthreads();
    if (tid == 0) {
        float t = 0.f;
        #pragma unroll
        for (int i = 0; i < 8; ++i) t += lsum[i];
        atomicAdd(out, t / (float)n);
    }
}

// ---- launch -----------------------------------------------------------------
extern "C" void kernel_launch(void* const* d_in, const int* in_sizes, int n_in,
                              void* d_out, int out_size, void* d_ws, size_t ws_size,
                              hipStream_t stream) {
    const float* z1 = (const float*)d_in[0];
    const float* z2 = (const float*)d_in[1];
    const int n = in_sizes[0] / 128;            // 8192

    char* ws = (char*)d_ws;
    short*    z1b    = (short*)ws;                                     // 2 MB
    short*    z2b    = (short*)(ws + (size_t)n * 128 * 2);             // 2 MB
    float*    sq1    = (float*)(ws + (size_t)n * 128 * 4);             // 32 KB
    float*    sq2    = (float*)(ws + (size_t)n * 128 * 4 + n * 4);     // 32 KB
    float*    posd   = (float*)(ws + (size_t)n * 128 * 4 + n * 8);     // 32 KB
    unsigned* rowmin = (unsigned*)(ws + (size_t)n * 128 * 4 + n * 12); // 32 KB
    unsigned* cnt    = (unsigned*)(ws + (size_t)n * 128 * 4 + n * 16); // 128 B
    float*    out    = (float*)d_out;

    prep_kernel<<<n / 16, 256, 0, stream>>>(z1, z2, z1b, z2b, sq1, sq2, posd,
                                            rowmin, cnt, out);
    gemm_min_kernel<<<(n / 512) * (n / 512), 512, 0, stream>>>(
        z1b, z2b, sq1, sq2, posd, rowmin, cnt, out, n);
}